// Round 6
// baseline (617.388 us; speedup 1.0000x reference)
//
#include <hip/hip_runtime.h>
#include <hip/hip_cooperative_groups.h>

namespace cg = cooperative_groups;

#define G_ 100
#define T_ 24
#define NSC 128
#define BATCH 8
#define NITER 40
#define NBLK (BATCH*T_)     // 192 WGs: one (batch,t) per WG
#define NTHR 512            // 8 waves -> 2 waves/SIMD
#define GMAX 15             // pass-A g's per wave (7 waves cover 100 g)

typedef unsigned long long u64;

// (tag<<32 | float) pairs via relaxed agent-scope 8B atomics (LLC-coherent).
// Consumers spin on tags; producers never fence. Depth-3 buffers, monotonic tags.
__device__ __forceinline__ u64 gload64(const u64* p){
  return __hip_atomic_load(p, __ATOMIC_RELAXED, __HIP_MEMORY_SCOPE_AGENT);
}
__device__ __forceinline__ void gstore64(u64* p, u64 v){
  __hip_atomic_store(p, v, __ATOMIC_RELAXED, __HIP_MEMORY_SCOPE_AGENT);
}
__device__ __forceinline__ u64 pack(float v, unsigned tag){
  return ((u64)tag<<32) | (u64)__float_as_uint(v);
}
__device__ __forceinline__ float unpackv(u64 x){ return __uint_as_float((unsigned)x); }
__device__ __forceinline__ unsigned unpackt(u64 x){ return (unsigned)(x>>32); }

// full-block reduce (init/epilogue only)
__device__ __forceinline__ void blockReduce2(float& a, float& b, float* sR){
#pragma unroll
  for (int off=32; off; off>>=1){ a+=__shfl_down(a,off,64); b+=__shfl_down(b,off,64); }
  const int w = threadIdx.x>>6;
  __syncthreads();
  if ((threadIdx.x&63)==0){ sR[w]=a; sR[8+w]=b; }
  __syncthreads();
  a=0.f; b=0.f;
#pragma unroll
  for (int i=0;i<8;++i){ a+=sR[i]; b+=sR[8+i]; }
}

__global__ __launch_bounds__(NTHR, 1) void dro_kernel(
    const float* __restrict__ forecast, const float* __restrict__ omega,
    const float* __restrict__ om_min, const float* __restrict__ om_max,
    const float* __restrict__ eps_in, const float* __restrict__ pmin_g,
    const float* __restrict__ pmax_g, const float* __restrict__ bG,
    const float* __restrict__ cG, float* __restrict__ out, float* __restrict__ ws)
{
  constexpr float LR=2e-4f, VOLL=1000.f, VOSP=50.f, TWO_RHO=20.f, INVN=1.f/128.f;
  constexpr float GQ1=0.5f*INVN, GQ2=1.0f*INVN;   // exact representable gq values
  const int blk=blockIdx.x;
  const int b=blk&7;            // round-robin XCD: batch stays XCD-affine
  const int t_own=blk>>3;
  const int tid=threadIdx.x, wave=tid>>6, lane=tid&63;
  // pass-A g ownership: wave1 is EXEMPT (dedicated pass-B wave).
  // waves {0,2,3,4,5,6,7} own {14,15,15,14,14,14,14} g's = 100.
  int gbase, gcnt;
  if      (wave==0){ gbase=0;  gcnt=14; }
  else if (wave==1){ gbase=0;  gcnt=0;  }
  else if (wave==2){ gbase=14; gcnt=15; }
  else if (wave==3){ gbase=29; gcnt=15; }
  else             { gbase=44+(wave-4)*14; gcnt=14; }
  const bool pA = (wave!=1);

  __shared__ float sRu[2][G_], sRd[2][G_];   // double-buffered: passA reads cur, passB writes nxt
  __shared__ float sP[G_];                   // wave1-only during loop; epilogue reads
  __shared__ float sAccU[G_], sAccD[G_];
  __shared__ float sB[G_], sPmin[G_], sPmax[G_], sC[G_];
  __shared__ float sLS[NSC], sSP[NSC], sOm[NSC];
  __shared__ float sQn[NSC], sDM[NSC], sDm[NSC], sS2[NSC];
  __shared__ float sQp[NSC*9], sSp[NSC*9];   // [n][wave] stride 9; column 1 fixed 0
  __shared__ float sQnP[NTHR];
  __shared__ float sRed[40];
  __shared__ float sScal[8];   // parity slots: [par*3+{0,1,2}] = Qmax,Qmin,gamma for state k
  __shared__ unsigned sCnt[2]; // parity combine-ready counters (6 producer waves each)

  u64* W = (u64*)ws;
  u64* QNP = W;                       // [3][8][24][128]
  u64* PP  = W + 73728;               // [3][8][24][128] (first 100 used)
  u64* QS  = W + 147456;              // [3][8][24][16]  (Qmax@0, Qmin@1)
  u64* GAM = W + 156672;              // [3][8][16]
  u64* ST1 = W + 157056;              // [8][24][16]

  const float epsv  = eps_in[b];
  const float omaxT = om_max[b*T_ + t_own];
  const float ominT = om_min[b*T_ + t_own];
  const float fctT  = forecast[b*T_ + t_own];

  // register-resident d_up/d_dn: lane holds n=lane (A) and n=lane+64 (B)
  float duA[GMAX], duB[GMAX], ddA[GMAX], ddB[GMAX];
  // 3-variant precomputed per-wave partial sums (for gq in {0, GQ1, GQ2})
  float qvA0=0.f,qvA1=0.f,qvA2=0.f, svA0=0.f,svA1=0.f,svA2=0.f;
  float qvB0=0.f,qvB1=0.f,qvB2=0.f, svB0=0.f,svB1=0.f,svB2=0.f;
  float gQnA=0.f, gQnB=0.f;          // selected weights (phase2 -> phase3 materialize)
  float r220Ac=0.f, r220Bc=0.f;      // r220 of CURRENT state (for materialize)
  // wave1-resident pass-B state (2 g/lane: g=lane, g=lane+64 for lane<36)
  float duMr[2]={0.f,0.f}, ddMr[2]={0.f,0.f}, dumr[2]={0.f,0.f}, ddmr[2]={0.f,0.f};
  float lsm=0.f, spm=0.f, lsn=0.f, spn=0.f;     // wave1-lane0: LSM,SPM,LSm,SPm
  float r3reg=0.f, r4reg=0.f, rPreg=0.f;        // wave1-lane0

  // ---------------- init ----------------
  if (tid<G_){
    sB[tid]=bG[tid]; sPmin[tid]=pmin_g[tid]; sPmax[tid]=pmax_g[tid]; sC[tid]=cG[tid];
    sRu[0][tid]=0.f; sRd[0][tid]=0.f;
    sAccU[tid]=0.f; sAccD[tid]=0.f;
  }
  if (tid<NSC){
    const int nn=tid;
    sLS[nn]=0.f; sSP[nn]=0.f; sS2[nn]=0.f;
    sOm[nn]=omega[(b*NSC+nn)*T_+t_own];
    float dM=0.f,dm=0.f;
    for (int t=0;t<T_;++t){
      float o=omega[(b*NSC+nn)*T_+t];
      dM+=om_max[b*T_+t]-o; dm+=o-om_min[b*T_+t];
    }
    sDM[nn]=dM; sDm[nn]=dm;
    sQp[nn*9+1]=0.f; sSp[nn*9+1]=0.f;   // wave1 pass-A column: permanently zero
  }
  if (tid<6) sScal[tid]=0.f;            // state-0 Qmax/Qmin/gamma = 0 (both parity slots)
  if (tid==0){ sCnt[0]=0u; sCnt[1]=0u; }
  __syncthreads();
#pragma unroll
  for (int j=0;j<GMAX;++j){ duA[j]=0.f; duB[j]=0.f; ddA[j]=0.f; ddB[j]=0.f; }
  {
    float p0=0.f;
    if (tid<G_){
      p0=0.5f*(sPmin[tid]+sPmax[tid]);
      sP[tid]=p0;
      gstore64(&PP[b*3072 + t_own*128 + tid], pack(p0,1u));
    }
    if (tid<NSC) gstore64(&QNP[b*3072 + t_own*128 + tid], pack(0.f,1u));
    float rp=p0, dum0=0.f;
    blockReduce2(rp,dum0,sRed);
    r3reg=-omaxT; r4reg=-ominT; rPreg=rp-fctT;   // wave1-lane0's copies are live
  }
  __syncthreads();
  // variant precompute for k=0 (du=dd=0, Ru=Rd=0 in sRu[0]; LS/SP/S2=0)
  if (pA){
    const float r2A = sS2[lane]+sLS[lane]-sSP[lane]-sOm[lane];
    const float r2B = sS2[lane+64]+sLS[lane+64]-sSP[lane+64]-sOm[lane+64];
    r220Ac = TWO_RHO*r2A; r220Bc = TWO_RHO*r2B;
#pragma unroll
    for (int j=0;j<GMAX;++j){
      if (j<gcnt){
        const int g=gbase+j;
        const float bg=sB[g];
        const float rtu=2.f*bg, rtd=0.5f*bg;
        const float ru=sRu[0][g], rd=sRd[0][g];
        const float m7A=fmaxf(duA[j]-ru,0.f), m8A=fmaxf(ddA[j]-rd,0.f);
        const float m7B=fmaxf(duB[j]-ru,0.f), m8B=fmaxf(ddB[j]-rd,0.f);
        const float du0A=fmaxf(duA[j]-LR*(0.f*rtu+(r220Ac+TWO_RHO*m7A)),0.f);
        const float dd0A=fmaxf(ddA[j]-LR*(0.f*rtd+(TWO_RHO*m8A-r220Ac)),0.f);
        const float du1A=fmaxf(duA[j]-LR*(GQ1*rtu+(r220Ac+TWO_RHO*m7A)),0.f);
        const float dd1A=fmaxf(ddA[j]-LR*(GQ1*rtd+(TWO_RHO*m8A-r220Ac)),0.f);
        const float du2A=fmaxf(duA[j]-LR*(GQ2*rtu+(r220Ac+TWO_RHO*m7A)),0.f);
        const float dd2A=fmaxf(ddA[j]-LR*(GQ2*rtd+(TWO_RHO*m8A-r220Ac)),0.f);
        qvA0+=rtu*du0A+rtd*dd0A; svA0+=du0A-dd0A;
        qvA1+=rtu*du1A+rtd*dd1A; svA1+=du1A-dd1A;
        qvA2+=rtu*du2A+rtd*dd2A; svA2+=du2A-dd2A;
        const float du0B=fmaxf(duB[j]-LR*(0.f*rtu+(r220Bc+TWO_RHO*m7B)),0.f);
        const float dd0B=fmaxf(ddB[j]-LR*(0.f*rtd+(TWO_RHO*m8B-r220Bc)),0.f);
        const float du1B=fmaxf(duB[j]-LR*(GQ1*rtu+(r220Bc+TWO_RHO*m7B)),0.f);
        const float dd1B=fmaxf(ddB[j]-LR*(GQ1*rtd+(TWO_RHO*m8B-r220Bc)),0.f);
        const float du2B=fmaxf(duB[j]-LR*(GQ2*rtu+(r220Bc+TWO_RHO*m7B)),0.f);
        const float dd2B=fmaxf(ddB[j]-LR*(GQ2*rtd+(TWO_RHO*m8B-r220Bc)),0.f);
        qvB0+=rtu*du0B+rtd*dd0B; svB0+=du0B-dd0B;
        qvB1+=rtu*du1B+rtd*dd1B; svB1+=du1B-dd1B;
        qvB2+=rtu*du2B+rtd*dd2B; svB2+=du2B-dd2B;
      }
    }
  }

  for (int k=0;k<=NITER;++k){
    const unsigned tg  = (unsigned)(k+1);
    const unsigned tg2 = (unsigned)(k+2);
    const int rb = k%3, wb = (k+1)%3;
    const int kb = k&1, nbuf = kb^1;
    const int par = k&1, parN = par^1;
    float* sRuC = sRu[kb];  float* sRdC = sRd[kb];
    float* sRuN = sRu[nbuf]; float* sRdN = sRd[nbuf];
    const u64* qnpR = QNP + rb*24576 + b*3072;
    const u64* ppR  = PP  + rb*24576 + b*3072;
    u64* qnpW = QNP + wb*24576 + b*3072 + t_own*128;
    u64* ppW  = PP  + wb*24576 + b*3072 + t_own*128;
    u64* qsW  = QS  + (wb*BATCH + b)*T_*16 + t_own*16;
    const u64* qsN = QS + (wb*BATCH + b)*T_*16;   // consumed at PHASE 3 this iter (tag tg2)
    u64* gamW = GAM + (wb*BATCH + b)*16;
    const u64* gamN = gamW;

    // ---- PHASE 1: consume qnp (all) + neighbor P (wave1): pre-issue, unified spin ----
    const int n = tid&127, sb0 = (tid>>7)*6;
    const bool w1 = (wave==1), hasG1 = w1 && (lane<36);
    const bool doP = w1 && (k<NITER);
    u64 xq[6];
#pragma unroll
    for (int s=0;s<6;++s) xq[s]=gload64(&qnpR[(sb0+s)*128+n]);
    u64 xm0=0,xm1=0,xp0=0,xp1=0;
    if (doP){
      if (t_own>0){
        xm0=gload64(&ppR[(t_own-1)*128+lane]);
        if (hasG1) xm1=gload64(&ppR[(t_own-1)*128+lane+64]);
      }
      if (t_own<T_-1){
        xp0=gload64(&ppR[(t_own+1)*128+lane]);
        if (hasG1) xp1=gload64(&ppR[(t_own+1)*128+lane+64]);
      }
    }
    for (;;){
      bool pend=false;
#pragma unroll
      for (int s=0;s<6;++s)
        if (unpackt(xq[s])!=tg){ xq[s]=gload64(&qnpR[(sb0+s)*128+n]); pend=true; }
      if (doP){
        if (t_own>0){
          if (unpackt(xm0)!=tg){ xm0=gload64(&ppR[(t_own-1)*128+lane]); pend=true; }
          if (hasG1 && unpackt(xm1)!=tg){ xm1=gload64(&ppR[(t_own-1)*128+lane+64]); pend=true; }
        }
        if (t_own<T_-1){
          if (unpackt(xp0)!=tg){ xp0=gload64(&ppR[(t_own+1)*128+lane]); pend=true; }
          if (hasG1 && unpackt(xp1)!=tg){ xp1=gload64(&ppR[(t_own+1)*128+lane+64]); pend=true; }
        }
      }
      if (!pend) break;
      __builtin_amdgcn_s_sleep(1);
    }
    sQnP[tid]=unpackv(xq[0])+unpackv(xq[1])+unpackv(xq[2])
             +unpackv(xq[3])+unpackv(xq[4])+unpackv(xq[5]);
    __syncthreads();   // barrier A

    if (k==NITER){  // ---------------- final: phi + outputs ----------------
      const float Qm=sScal[par*3], Qn2=sScal[par*3+1], gam=sScal[par*3+2];
      if (tid<NSC){
        const float qsum=sQnP[tid]+sQnP[tid+128]+sQnP[tid+256]+sQnP[tid+384];
        const float ph=fmaxf(qsum,fmaxf(Qm-gam*sDM[tid],Qn2-gam*sDm[tid]));
        sQn[tid]=ph;
        if (t_own==0) out[76800 + b*NSC + tid]=ph;
      }
      float st=0.f, dum0=0.f;
      if (tid<G_){
        const int g=tid;
        const float Pv=sP[g];
        const float costv=sB[g]*Pv+sC[g];
        st=costv + 0.05f*sB[g]*sRuC[g] + 0.02f*sB[g]*sRdC[g];
        const int o=b*2400 + g*T_ + t_own;
        out[o]=Pv;
        out[19200+o]=sRuC[g];
        out[38400+o]=sRdC[g];
        out[57600+o]=costv;
      }
      blockReduce2(st,dum0,sRed);
      if (tid==0) gstore64(&ST1[(b*T_+t_own)*16], pack(st,99u));
      if (t_own==0){
        if (tid==0) out[77824+b]=gam;
        float s1=0.f;
        if (tid<64){
          u64 xs = (lane<T_)? gload64(&ST1[(b*T_+lane)*16]) : pack(0.f,99u);
          while (unpackt(xs)!=99u){ __builtin_amdgcn_s_sleep(1); xs=gload64(&ST1[(b*T_+lane)*16]); }
          s1=unpackv(xs);
        }
        float pm=(tid<NSC)? sQn[tid] : 0.f;
        blockReduce2(pm,s1,sRed);
        if (tid==0) out[77832+b] = s1 + pm*INVN + epsv*gam;
      }
      break;
    }

    // ---- PHASE 2: pass-A waves {gq + SELECT precomputed sums}; wave0 additionally
    //      {LS/SP update + counter-spin + combine + EARLY qnp publish};
    //      wave1 {weights-reduce + gamma + pass B + qs publish} ----
    const float QmaxS=sScal[par*3], QminS=sScal[par*3+1], gammaS=sScal[par*3+2];
    if (pA){
      float lsnA=0.f,spnA=0.f,lsnB=0.f,spnB=0.f;   // wave0 only
#pragma unroll
      for (int h=0;h<2;++h){
        const int nn=lane+h*64;
        const float Qn=sQnP[nn]+sQnP[nn+128]+sQnP[nn+256]+sQnP[nn+384];
        const float m1=QmaxS-gammaS*sDM[nn], m2=QminS-gammaS*sDm[nn];
        const float inner=fmaxf(m1,m2), ph=fmaxf(Qn,inner);
        const float gQn=(Qn==ph?1.f:0.f)/((inner==ph)?2.f:1.f);
        if (h==0) gQnA=gQn; else gQnB=gQn;
        if (wave==0){
          const float gq=gQn*INVN;
          const float r2=sS2[nn]+sLS[nn]-sSP[nn]-sOm[nn];
          const float r220=TWO_RHO*r2;
          const float lsnew=fmaxf(sLS[nn]-LR*(gq*VOLL+r220),0.f);
          const float spnew=fmaxf(sSP[nn]-LR*(gq*VOSP-r220),0.f);
          sLS[nn]=lsnew; sSP[nn]=spnew;
          if (h==0){ lsnA=lsnew; spnA=spnew; } else { lsnB=lsnew; spnB=spnew; }
        }
      }
      // select the precomputed per-wave sums matching gq (exact compares)
      const float qvA = (gQnA==0.f)? qvA0 : ((gQnA==0.5f)? qvA1 : qvA2);
      const float svA = (gQnA==0.f)? svA0 : ((gQnA==0.5f)? svA1 : svA2);
      const float qvB = (gQnB==0.f)? qvB0 : ((gQnB==0.5f)? qvB1 : qvB2);
      const float svB = (gQnB==0.f)? svB0 : ((gQnB==0.5f)? svB1 : svB2);
      sQp[lane*9+wave]=qvA;      sSp[lane*9+wave]=svA;
      sQp[(lane+64)*9+wave]=qvB; sSp[(lane+64)*9+wave]=svB;
      __threadfence_block();
      if (wave!=0){
        if (lane==0)
          __hip_atomic_fetch_add(&sCnt[par],1u,__ATOMIC_RELEASE,__HIP_MEMORY_SCOPE_WORKGROUP);
      } else {
        while (__hip_atomic_load(&sCnt[par],__ATOMIC_ACQUIRE,__HIP_MEMORY_SCOPE_WORKGROUP)!=6u)
          __builtin_amdgcn_s_sleep(1);
        __threadfence_block();
        // combine (today's exact w=0..7 order) + EARLY qnp publish
#pragma unroll
        for (int h=0;h<2;++h){
          const int nn=lane+h*64;
          float q=0.f,s=0.f;
#pragma unroll
          for (int w=0;w<8;++w){ q+=sQp[nn*9+w]; s+=sSp[nn*9+w]; }
          sS2[nn]=s;
          q += VOLL*(h?lsnB:lsnA) + VOSP*(h?spnB:spnA);
          gstore64(&qnpW[nn], pack(q,tg2));
        }
        if (lane==0) sCnt[par]=0u;   // reset; ordered vs reuse by barriers C,A,C,A
      }
    } else {
      // wave1: weight reductions S1s/S2s/sgl (bit-identical), gamma publish, pass B.
      float g1l=0.f,g2l=0.f,sgl=0.f;
#pragma unroll
      for (int h=0;h<2;++h){
        const int nn=lane+h*64;
        const float Qn=sQnP[nn]+sQnP[nn+128]+sQnP[nn+256]+sQnP[nn+384];
        const float m1=QmaxS-gammaS*sDM[nn], m2=QminS-gammaS*sDm[nn];
        const float inner=fmaxf(m1,m2), ph=fmaxf(Qn,inner);
        const float gQn=(Qn==ph?1.f:0.f)/((inner==ph)?2.f:1.f);
        const float gIn=(inner==ph?1.f:0.f)/((Qn==ph)?2.f:1.f);
        const float gm1=gIn*(m1==inner?1.f:0.f)/((m2==inner)?2.f:1.f);
        const float gm2=gIn*(m2==inner?1.f:0.f)/((m1==inner)?2.f:1.f);
        g1l+=gm1; g2l+=gm2; sgl+=gm1*sDM[nn]+gm2*sDm[nn];
        (void)gQn;
      }
#pragma unroll
      for (int off=32; off; off>>=1){
        g1l+=__shfl_xor(g1l,off,64); g2l+=__shfl_xor(g2l,off,64); sgl+=__shfl_xor(sgl,off,64);
      }
      const float S1s=g1l, S2s=g2l;   // uniform across wave after butterfly
      if (t_own==0 && lane==0)
        gstore64(gamW, pack(fmaxf(gammaS-LR*(epsv-INVN*sgl),0.f), tg2));
      // pass B (deps: consume + barrier A only — NOT pass A)
      const float r3=__shfl(r3reg,0,64), r4=__shfl(r4reg,0,64), rP=__shfl(rPreg,0,64);
      float pQx=0.f,pQn2=0.f,pr3=0.f,pr4=0.f,pP=0.f;
#pragma unroll
      for (int i=0;i<2;++i){
        if (i==0 || hasG1){
          const int g = lane + i*64;
          const float rupS=sAccU[g], rdnS=sAccD[g];
          const float Pold=sP[g], ru=sRuC[g], rd=sRdC[g];
          const float duMo=duMr[i], ddMo=ddMr[i], dumo=dumr[i], ddmo=ddmr[i];
          const float r5 =fmaxf(Pold+ru-sPmax[g],0.f);
          const float r6 =fmaxf(sPmin[g]-Pold+rd,0.f);
          const float r9 =fmaxf(duMo-ru,0.f), r10=fmaxf(ddMo-rd,0.f);
          const float r11=fmaxf(dumo-ru,0.f), r12=fmaxf(ddmo-rd,0.f);
          const float rampg=sPmax[g];
          float gP=sB[g]+TWO_RHO*(rP+r5-r6);
          if (t_own>0){
            const float dp=Pold-unpackv(i==0?xm0:xm1);
            gP+=TWO_RHO*fmaxf(fabsf(dp)-rampg,0.f)*(dp>=0.f?1.f:-1.f);
          }
          if (t_own<T_-1){
            const float dq=unpackv(i==0?xp0:xp1)-Pold;
            gP-=TWO_RHO*fmaxf(fabsf(dq)-rampg,0.f)*(dq>=0.f?1.f:-1.f);
          }
          const float Pn=fminf(fmaxf(Pold-LR*gP,sPmin[g]),sPmax[g]);
          sP[g]=Pn; gstore64(&ppW[g], pack(Pn,tg2));
          const float rtuB=2.f*sB[g], rtdB=0.5f*sB[g];
          sRuN[g]=fmaxf(ru-LR*(0.05f*sB[g]+TWO_RHO*(r5-rupS-r9-r11)),0.f);
          sRdN[g]=fmaxf(rd-LR*(0.02f*sB[g]+TWO_RHO*(r6-rdnS-r10-r12)),0.f);
          const float duMn=fmaxf(duMo-LR*(INVN*S1s*rtuB+TWO_RHO*( r3+r9 )),0.f);
          const float ddMn=fmaxf(ddMo-LR*(INVN*S1s*rtdB+TWO_RHO*(-r3+r10)),0.f);
          const float dumn=fmaxf(dumo-LR*(INVN*S2s*rtuB+TWO_RHO*( r4+r11)),0.f);
          const float ddmn=fmaxf(ddmo-LR*(INVN*S2s*rtdB+TWO_RHO*(-r4+r12)),0.f);
          duMr[i]=duMn; ddMr[i]=ddMn; dumr[i]=dumn; ddmr[i]=ddmn;
          pQx+=rtuB*duMn+rtdB*ddMn; pQn2+=rtuB*dumn+rtdB*ddmn;
          pr3+=duMn-ddMn; pr4+=dumn-ddmn; pP+=Pn;
        }
      }
#pragma unroll
      for (int off=32; off; off>>=1){
        pQx+=__shfl_down(pQx,off,64);  pQn2+=__shfl_down(pQn2,off,64);
        pr3+=__shfl_down(pr3,off,64);  pr4+=__shfl_down(pr4,off,64);
        pP +=__shfl_down(pP,off,64);
      }
      if (lane==0){
        const float LSMn=fmaxf(lsm-LR*(INVN*S1s*VOLL+TWO_RHO*r3),0.f);
        const float SPMn=fmaxf(spm-LR*(INVN*S1s*VOSP-TWO_RHO*r3),0.f);
        const float LSmn=fmaxf(lsn-LR*(INVN*S2s*VOLL+TWO_RHO*r4),0.f);
        const float SPmn=fmaxf(spn-LR*(INVN*S2s*VOSP-TWO_RHO*r4),0.f);
        lsm=LSMn; spm=SPMn; lsn=LSmn; spn=SPmn;
        gstore64(&qsW[0], pack(pQx + VOLL*LSMn + VOSP*SPMn, tg2));   // qs lands EARLY
        gstore64(&qsW[1], pack(pQn2 + VOLL*LSmn + VOSP*SPmn, tg2));
        r3reg=pr3 + LSMn - SPMn - omaxT;
        r4reg=pr4 + LSmn - SPmn - ominT;
        rPreg=pP - fctT;
      }
    }
    __syncthreads();   // barrier C (last barrier of the iteration)

    // ---- PHASE 3 (hidden under inter-WG latency):
    //      pass-A waves {materialize du/dd + shadow + next-iter 3-variant precompute};
    //      wave1 {qs/gamma spin -> sScal[parN]} ----
    if (pA){
      const float gqA=gQnA*INVN, gqB=gQnB*INVN;
      // next-state r220 (state k+1: sS2/sLS/sSP written by wave0 this phase 2)
      const float r2An = sS2[lane]+sLS[lane]-sSP[lane]-sOm[lane];
      const float r2Bn = sS2[lane+64]+sLS[lane+64]-sSP[lane+64]-sOm[lane+64];
      const float r220An=TWO_RHO*r2An, r220Bn=TWO_RHO*r2Bn;
      qvA0=0.f;qvA1=0.f;qvA2=0.f; svA0=0.f;svA1=0.f;svA2=0.f;
      qvB0=0.f;qvB1=0.f;qvB2=0.f; svB0=0.f;svB1=0.f;svB2=0.f;
#pragma unroll
      for (int j=0;j<GMAX;++j){
        if (j<gcnt){
          const int g=gbase+j;
          const float bg=sB[g];
          const float rtu=2.f*bg, rtd=0.5f*bg;
          // materialize du/dd(k+1): exact same exprs the variants used last phase 3
          const float ruC=sRuC[g], rdC=sRdC[g];
          const float r7A=fmaxf(duA[j]-ruC,0.f), r8A=fmaxf(ddA[j]-rdC,0.f);
          const float r7B=fmaxf(duB[j]-ruC,0.f), r8B=fmaxf(ddB[j]-rdC,0.f);
          duA[j]=fmaxf(duA[j]-LR*(gqA*rtu+(r220Ac+TWO_RHO*r7A)),0.f);
          ddA[j]=fmaxf(ddA[j]-LR*(gqA*rtd+(TWO_RHO*r8A-r220Ac)),0.f);
          duB[j]=fmaxf(duB[j]-LR*(gqB*rtu+(r220Bc+TWO_RHO*r7B)),0.f);
          ddB[j]=fmaxf(ddB[j]-LR*(gqB*rtd+(TWO_RHO*r8B-r220Bc)),0.f);
          // shadow with NEW Ru/Rd (pass B done at barrier C)
          const float ruN=sRuN[g], rdN=sRdN[g];
          const float m7A=fmaxf(duA[j]-ruN,0.f), m7B=fmaxf(duB[j]-ruN,0.f);
          const float m8A=fmaxf(ddA[j]-rdN,0.f), m8B=fmaxf(ddB[j]-rdN,0.f);
          float aU=m7A+m7B;
          float aD=m8A+m8B;
#pragma unroll
          for (int off=32; off; off>>=1){ aU+=__shfl_xor(aU,off,64); aD+=__shfl_xor(aD,off,64); }
          if (lane==0){ sAccU[g]=aU; sAccD[g]=aD; }
          // 3-variant precompute for next iteration (m7/m8 are its r7/r8)
          const float du0A=fmaxf(duA[j]-LR*(0.f*rtu+(r220An+TWO_RHO*m7A)),0.f);
          const float dd0A=fmaxf(ddA[j]-LR*(0.f*rtd+(TWO_RHO*m8A-r220An)),0.f);
          const float du1A=fmaxf(duA[j]-LR*(GQ1*rtu+(r220An+TWO_RHO*m7A)),0.f);
          const float dd1A=fmaxf(ddA[j]-LR*(GQ1*rtd+(TWO_RHO*m8A-r220An)),0.f);
          const float du2A=fmaxf(duA[j]-LR*(GQ2*rtu+(r220An+TWO_RHO*m7A)),0.f);
          const float dd2A=fmaxf(ddA[j]-LR*(GQ2*rtd+(TWO_RHO*m8A-r220An)),0.f);
          qvA0+=rtu*du0A+rtd*dd0A; svA0+=du0A-dd0A;
          qvA1+=rtu*du1A+rtd*dd1A; svA1+=du1A-dd1A;
          qvA2+=rtu*du2A+rtd*dd2A; svA2+=du2A-dd2A;
          const float du0B=fmaxf(duB[j]-LR*(0.f*rtu+(r220Bn+TWO_RHO*m7B)),0.f);
          const float dd0B=fmaxf(ddB[j]-LR*(0.f*rtd+(TWO_RHO*m8B-r220Bn)),0.f);
          const float du1B=fmaxf(duB[j]-LR*(GQ1*rtu+(r220Bn+TWO_RHO*m7B)),0.f);
          const float dd1B=fmaxf(ddB[j]-LR*(GQ1*rtd+(TWO_RHO*m8B-r220Bn)),0.f);
          const float du2B=fmaxf(duB[j]-LR*(GQ2*rtu+(r220Bn+TWO_RHO*m7B)),0.f);
          const float dd2B=fmaxf(ddB[j]-LR*(GQ2*rtd+(TWO_RHO*m8B-r220Bn)),0.f);
          qvB0+=rtu*du0B+rtd*dd0B; svB0+=du0B-dd0B;
          qvB1+=rtu*du1B+rtd*dd1B; svB1+=du1B-dd1B;
          qvB2+=rtu*du2B+rtd*dd2B; svB2+=du2B-dd2B;
        }
      }
      r220Ac=r220An; r220Bc=r220Bn;
    } else {
      // wave1: pre-issue + spin for next-state qs/gamma; reduce into sScal[parN]
      u64 yq0=0, yq1=0, yg;
      if (lane<T_){ yq0=gload64(&qsN[lane*16]); yq1=gload64(&qsN[lane*16+1]); }
      yg=gload64(gamN);
      for (;;){
        bool pend=false;
        if (lane<T_){
          if (unpackt(yq0)!=tg2){ yq0=gload64(&qsN[lane*16]);   pend=true; }
          if (unpackt(yq1)!=tg2){ yq1=gload64(&qsN[lane*16+1]); pend=true; }
        }
        if (unpackt(yg)!=tg2){ yg=gload64(gamN); pend=true; }
        if (!pend) break;
        __builtin_amdgcn_s_sleep(1);
      }
      float qmx=(lane<T_)?unpackv(yq0):0.f, qmn=(lane<T_)?unpackv(yq1):0.f;
#pragma unroll
      for (int off=32; off; off>>=1){ qmx+=__shfl_xor(qmx,off,64); qmn+=__shfl_xor(qmn,off,64); }
      if (lane==0){ sScal[parN*3]=qmx; sScal[parN*3+1]=qmn; sScal[parN*3+2]=unpackv(yg); }
    }
    // no barrier here: barrier A of the next iteration orders phase-3 writes
    // (sAcc/sScal/du-dd regs/variant regs) against all next-iteration readers.
  }
}

extern "C" void kernel_launch(void* const* d_in, const int* in_sizes, int n_in,
                              void* d_out, int out_size, void* d_ws, size_t ws_size,
                              hipStream_t stream) {
  const float* forecast = (const float*)d_in[0];
  const float* omega    = (const float*)d_in[1];
  const float* omin     = (const float*)d_in[2];
  const float* omax     = (const float*)d_in[3];
  const float* eps      = (const float*)d_in[4];
  const float* pmin     = (const float*)d_in[5];
  const float* pmax     = (const float*)d_in[6];
  const float* bG       = (const float*)d_in[7];
  const float* cG       = (const float*)d_in[8];
  float* out = (float*)d_out;
  float* ws  = (float*)d_ws;
  void* args[] = { &forecast, &omega, &omin, &omax, &eps, &pmin, &pmax, &bG, &cG, &out, &ws };
  hipLaunchCooperativeKernel((const void*)dro_kernel, dim3(NBLK), dim3(NTHR),
                             args, 0, stream);
}

// Round 8
// 427.644 us; speedup vs baseline: 1.4437x; 1.4437x over previous
//
#include <hip/hip_runtime.h>
#include <hip/hip_cooperative_groups.h>

namespace cg = cooperative_groups;

#define G_ 100
#define T_ 24
#define NSC 128
#define BATCH 8
#define NITER 40
#define NBLK (BATCH*T_)     // 192 WGs: one (batch,t) per WG
#define NTHR 512            // 8 waves -> 2 waves/SIMD
#define GMAX 15             // pass-A g's per wave (7 waves cover 100 g)

typedef unsigned long long u64;

// (tag<<32 | float) pairs via relaxed agent-scope 8B atomics (LLC-coherent).
// Consumers spin on tags; producers never fence. Depth-3 buffers, monotonic tags.
__device__ __forceinline__ u64 gload64(const u64* p){
  return __hip_atomic_load(p, __ATOMIC_RELAXED, __HIP_MEMORY_SCOPE_AGENT);
}
__device__ __forceinline__ void gstore64(u64* p, u64 v){
  __hip_atomic_store(p, v, __ATOMIC_RELAXED, __HIP_MEMORY_SCOPE_AGENT);
}
__device__ __forceinline__ u64 pack(float v, unsigned tag){
  return ((u64)tag<<32) | (u64)__float_as_uint(v);
}
__device__ __forceinline__ float unpackv(u64 x){ return __uint_as_float((unsigned)x); }
__device__ __forceinline__ unsigned unpackt(u64 x){ return (unsigned)(x>>32); }

// full-block reduce (init/epilogue only)
__device__ __forceinline__ void blockReduce2(float& a, float& b, float* sR){
#pragma unroll
  for (int off=32; off; off>>=1){ a+=__shfl_down(a,off,64); b+=__shfl_down(b,off,64); }
  const int w = threadIdx.x>>6;
  __syncthreads();
  if ((threadIdx.x&63)==0){ sR[w]=a; sR[8+w]=b; }
  __syncthreads();
  a=0.f; b=0.f;
#pragma unroll
  for (int i=0;i<8;++i){ a+=sR[i]; b+=sR[8+i]; }
}

// __launch_bounds__(512, 2): declare the TRUE occupancy (8 waves/WG, 1 WG/CU =
// 2 waves/SIMD). Raises the VGPR allocator cap 128 -> 256: the 128-pin caused
// scratch spills (WRITE_SIZE 16->28/844 MB) in every prior enhancement attempt.
__global__ __launch_bounds__(NTHR, 2) void dro_kernel(
    const float* __restrict__ forecast, const float* __restrict__ omega,
    const float* __restrict__ om_min, const float* __restrict__ om_max,
    const float* __restrict__ eps_in, const float* __restrict__ pmin_g,
    const float* __restrict__ pmax_g, const float* __restrict__ bG,
    const float* __restrict__ cG, float* __restrict__ out, float* __restrict__ ws)
{
  constexpr float LR=2e-4f, VOLL=1000.f, VOSP=50.f, TWO_RHO=20.f, INVN=1.f/128.f;
  const int blk=blockIdx.x;
  const int b=blk&7;            // round-robin XCD: batch stays XCD-affine
  const int t_own=blk>>3;
  const int tid=threadIdx.x, wave=tid>>6, lane=tid&63;
  // pass-A g ownership: wave1 is EXEMPT (dedicated pass-B/combine wave).
  // waves {0,2,3,4,5,6,7} own {14,15,15,14,14,14,14} g's = 100.
  int gbase, gcnt;
  if      (wave==0){ gbase=0;  gcnt=14; }
  else if (wave==1){ gbase=0;  gcnt=0;  }
  else if (wave==2){ gbase=14; gcnt=15; }
  else if (wave==3){ gbase=29; gcnt=15; }
  else             { gbase=44+(wave-4)*14; gcnt=14; }
  const bool pA = (wave!=1);

  __shared__ float sRu[2][G_], sRd[2][G_];   // double-buffered: passA reads cur, passB writes nxt
  __shared__ float sP[G_];                   // wave1-only during loop; epilogue reads
  __shared__ float sAccU[G_], sAccD[G_];
  __shared__ float sB[G_], sPmin[G_], sPmax[G_], sC[G_];
  __shared__ float sLS[NSC], sSP[NSC], sOm[NSC];
  __shared__ float sQn[NSC], sDM[NSC], sDm[NSC], sS2[NSC];
  __shared__ float sQp[NSC*9], sSp[NSC*9];   // [n][wave] stride 9; column 1 fixed 0
  __shared__ float sQnP[NTHR];
  __shared__ float sRed[40];
  __shared__ float sScal[8];   // parity slots: [par*3+{0,1,2}] = Qmax,Qmin,gamma for state k (par=k&1)

  u64* W = (u64*)ws;
  u64* QNP = W;                       // [3][8][24][128]
  u64* PP  = W + 73728;               // [3][8][24][128] (first 100 used)
  u64* QS  = W + 147456;              // [3][8][24][16]  (Qmax@0, Qmin@1)
  u64* GAM = W + 156672;              // [3][8][16]
  u64* ST1 = W + 157056;              // [8][24][16]

  const float epsv  = eps_in[b];
  const float omaxT = om_max[b*T_ + t_own];
  const float ominT = om_min[b*T_ + t_own];
  const float fctT  = forecast[b*T_ + t_own];

  // register-resident d_up/d_dn: lane holds n=lane (A) and n=lane+64 (B)
  float duA[GMAX], duB[GMAX], ddA[GMAX], ddB[GMAX];
  // wave1-resident pass-B state (2 g/lane: g=lane, g=lane+64 for lane<36)
  float duMr[2]={0.f,0.f}, ddMr[2]={0.f,0.f}, dumr[2]={0.f,0.f}, ddmr[2]={0.f,0.f};
  float lsm=0.f, spm=0.f, lsn=0.f, spn=0.f;     // wave1-lane0: LSM,SPM,LSm,SPm
  float r3reg=0.f, r4reg=0.f, rPreg=0.f;        // wave1-lane0

  // ---------------- init ----------------
  if (tid<G_){
    sB[tid]=bG[tid]; sPmin[tid]=pmin_g[tid]; sPmax[tid]=pmax_g[tid]; sC[tid]=cG[tid];
    sRu[0][tid]=0.f; sRd[0][tid]=0.f;
    sAccU[tid]=0.f; sAccD[tid]=0.f;
  }
  if (tid<NSC){
    const int nn=tid;
    sLS[nn]=0.f; sSP[nn]=0.f; sS2[nn]=0.f;
    sOm[nn]=omega[(b*NSC+nn)*T_+t_own];
    float dM=0.f,dm=0.f;
    for (int t=0;t<T_;++t){
      float o=omega[(b*NSC+nn)*T_+t];
      dM+=om_max[b*T_+t]-o; dm+=o-om_min[b*T_+t];
    }
    sDM[nn]=dM; sDm[nn]=dm;
    sQp[nn*9+1]=0.f; sSp[nn*9+1]=0.f;   // wave1 pass-A column: permanently zero
  }
  if (tid<6) sScal[tid]=0.f;            // state-0 Qmax/Qmin/gamma = 0 (both parity slots)
  __syncthreads();
#pragma unroll
  for (int j=0;j<GMAX;++j){ duA[j]=0.f; duB[j]=0.f; ddA[j]=0.f; ddB[j]=0.f; }
  {
    float p0=0.f;
    if (tid<G_){
      p0=0.5f*(sPmin[tid]+sPmax[tid]);
      sP[tid]=p0;
      gstore64(&PP[b*3072 + t_own*128 + tid], pack(p0,1u));
    }
    if (tid<NSC) gstore64(&QNP[b*3072 + t_own*128 + tid], pack(0.f,1u));
    float rp=p0, dum0=0.f;
    blockReduce2(rp,dum0,sRed);
    r3reg=-omaxT; r4reg=-ominT; rPreg=rp-fctT;   // wave1-lane0's copies are live
  }
  __syncthreads();

  for (int k=0;k<=NITER;++k){
    const unsigned tg  = (unsigned)(k+1);
    const unsigned tg2 = (unsigned)(k+2);
    const int rb = k%3, wb = (k+1)%3;
    const int kb = k&1, nbuf = kb^1;
    const int par = k&1, parN = par^1;
    float* sRuC = sRu[kb];  float* sRdC = sRd[kb];
    float* sRuN = sRu[nbuf]; float* sRdN = sRd[nbuf];
    const u64* qnpR = QNP + rb*24576 + b*3072;
    const u64* ppR  = PP  + rb*24576 + b*3072;
    u64* qnpW = QNP + wb*24576 + b*3072 + t_own*128;
    u64* ppW  = PP  + wb*24576 + b*3072 + t_own*128;
    u64* qsW  = QS  + (wb*BATCH + b)*T_*16 + t_own*16;
    const u64* qsN = QS + (wb*BATCH + b)*T_*16;   // consumed at PHASE 3 this iter (tag tg2)
    u64* gamW = GAM + (wb*BATCH + b)*16;
    const u64* gamN = gamW;

    // ---- PHASE 1: issue qnp polls FIRST; pass-A waves run the SHADOW of the
    //      previous iteration under the poll RTT; then unified verify spin ----
    const int n = tid&127, sb0 = (tid>>7)*6;
    const bool w1 = (wave==1), hasG1 = w1 && (lane<36);
    const bool doP = w1 && (k<NITER);
    u64 xq[6];
#pragma unroll
    for (int s=0;s<6;++s) xq[s]=gload64(&qnpR[(sb0+s)*128+n]);
    u64 xm0=0,xm1=0,xp0=0,xp1=0;
    if (doP){
      if (t_own>0){
        xm0=gload64(&ppR[(t_own-1)*128+lane]);
        if (hasG1) xm1=gload64(&ppR[(t_own-1)*128+lane+64]);
      }
      if (t_own<T_-1){
        xp0=gload64(&ppR[(t_own+1)*128+lane]);
        if (hasG1) xp1=gload64(&ppR[(t_own+1)*128+lane+64]);
      }
    }
    if (pA && k>0){
      // shadow of state k (du/dd in regs from phase 2 of k-1; Ru/Rd of state k
      // = sRuC of THIS iter, ordered by barrier C of k-1): same arithmetic as
      // the old phase-3 shadow, hidden under the in-flight qnp polls.
      // sAccU/sAccD writes are ordered before wave1's pass-B read by barrier A.
#pragma unroll
      for (int j=0;j<GMAX;++j){
        if (j<gcnt){
          const int g=gbase+j;
          const float ru=sRuC[g], rd=sRdC[g];
          float aU=fmaxf(duA[j]-ru,0.f)+fmaxf(duB[j]-ru,0.f);
          float aD=fmaxf(ddA[j]-rd,0.f)+fmaxf(ddB[j]-rd,0.f);
#pragma unroll
          for (int off=32; off; off>>=1){ aU+=__shfl_xor(aU,off,64); aD+=__shfl_xor(aD,off,64); }
          if (lane==0){ sAccU[g]=aU; sAccD[g]=aD; }
        }
      }
    }
    for (;;){
      bool pend=false;
#pragma unroll
      for (int s=0;s<6;++s)
        if (unpackt(xq[s])!=tg){ xq[s]=gload64(&qnpR[(sb0+s)*128+n]); pend=true; }
      if (doP){
        if (t_own>0){
          if (unpackt(xm0)!=tg){ xm0=gload64(&ppR[(t_own-1)*128+lane]); pend=true; }
          if (hasG1 && unpackt(xm1)!=tg){ xm1=gload64(&ppR[(t_own-1)*128+lane+64]); pend=true; }
        }
        if (t_own<T_-1){
          if (unpackt(xp0)!=tg){ xp0=gload64(&ppR[(t_own+1)*128+lane]); pend=true; }
          if (hasG1 && unpackt(xp1)!=tg){ xp1=gload64(&ppR[(t_own+1)*128+lane+64]); pend=true; }
        }
      }
      if (!pend) break;
      __builtin_amdgcn_s_sleep(1);
    }
    sQnP[tid]=unpackv(xq[0])+unpackv(xq[1])+unpackv(xq[2])
             +unpackv(xq[3])+unpackv(xq[4])+unpackv(xq[5]);
    __syncthreads();   // barrier A

    if (k==NITER){  // ---------------- final: phi + outputs ----------------
      // state-40 Qmax/Qmin/gamma were consumed+reduced at phase 3 of k=39 into slot par
      const float Qm=sScal[par*3], Qn2=sScal[par*3+1], gam=sScal[par*3+2];
      if (tid<NSC){
        const float qsum=sQnP[tid]+sQnP[tid+128]+sQnP[tid+256]+sQnP[tid+384];
        const float ph=fmaxf(qsum,fmaxf(Qm-gam*sDM[tid],Qn2-gam*sDm[tid]));
        sQn[tid]=ph;
        if (t_own==0) out[76800 + b*NSC + tid]=ph;
      }
      float st=0.f, dum0=0.f;
      if (tid<G_){
        const int g=tid;
        const float Pv=sP[g];
        const float costv=sB[g]*Pv+sC[g];
        st=costv + 0.05f*sB[g]*sRuC[g] + 0.02f*sB[g]*sRdC[g];
        const int o=b*2400 + g*T_ + t_own;
        out[o]=Pv;
        out[19200+o]=sRuC[g];
        out[38400+o]=sRdC[g];
        out[57600+o]=costv;
      }
      blockReduce2(st,dum0,sRed);
      if (tid==0) gstore64(&ST1[(b*T_+t_own)*16], pack(st,99u));
      if (t_own==0){
        if (tid==0) out[77824+b]=gam;
        float s1=0.f;
        if (tid<64){
          u64 xs = (lane<T_)? gload64(&ST1[(b*T_+lane)*16]) : pack(0.f,99u);
          while (unpackt(xs)!=99u){ __builtin_amdgcn_s_sleep(1); xs=gload64(&ST1[(b*T_+lane)*16]); }
          s1=unpackv(xs);
        }
        float pm=(tid<NSC)? sQn[tid] : 0.f;
        blockReduce2(pm,s1,sRed);
        if (tid==0) out[77832+b] = s1 + pm*INVN + epsv*gam;
      }
      break;
    }

    // ---- PHASE 2: pass A (7 waves, with per-lane weight recompute)
    //               CONCURRENT WITH wave1 {weights-reduce + gamma + pass B + qs publish} ----
    const float QmaxS=sScal[par*3], QminS=sScal[par*3+1], gammaS=sScal[par*3+2];
    float lsR0=0.f, lsR1=0.f, spR0=0.f, spR1=0.f;   // wave1: precomputed LS/SP updates
    if (pA){
      // redundant per-lane weights for n=lane (A) and n=lane+64 (B): bit-identical.
      float gqA=0.f,r220A=0.f,gqB=0.f,r220B=0.f;
#pragma unroll
      for (int h=0;h<2;++h){
        const int nn=lane+h*64;
        const float Qn=sQnP[nn]+sQnP[nn+128]+sQnP[nn+256]+sQnP[nn+384];
        const float m1=QmaxS-gammaS*sDM[nn], m2=QminS-gammaS*sDm[nn];
        const float inner=fmaxf(m1,m2), ph=fmaxf(Qn,inner);
        const float gQn=(Qn==ph?1.f:0.f)/((inner==ph)?2.f:1.f);
        const float gq=gQn*INVN;
        const float r2=sS2[nn]+sLS[nn]-sSP[nn]-sOm[nn];
        const float r220=TWO_RHO*r2;
        if (h==0){ gqA=gq; r220A=r220; } else { gqB=gq; r220B=r220; }
      }
      float qvA=0.f,qvB=0.f,svA=0.f,svB=0.f;
#pragma unroll
      for (int j=0;j<GMAX;++j){
        if (j<gcnt){
          const int g=gbase+j;
          const float bg=sB[g];
          const float rtu=2.f*bg, rtd=0.5f*bg;
          const float ru=sRuC[g], rd=sRdC[g];
          const float r7A=fmaxf(duA[j]-ru,0.f), r8A=fmaxf(ddA[j]-rd,0.f);
          const float r7B=fmaxf(duB[j]-ru,0.f), r8B=fmaxf(ddB[j]-rd,0.f);
          duA[j]=fmaxf(duA[j]-LR*(gqA*rtu+(r220A+TWO_RHO*r7A)),0.f);
          ddA[j]=fmaxf(ddA[j]-LR*(gqA*rtd+(TWO_RHO*r8A-r220A)),0.f);
          duB[j]=fmaxf(duB[j]-LR*(gqB*rtu+(r220B+TWO_RHO*r7B)),0.f);
          ddB[j]=fmaxf(ddB[j]-LR*(gqB*rtd+(TWO_RHO*r8B-r220B)),0.f);
          qvA+=rtu*duA[j]+rtd*ddA[j];  svA+=duA[j]-ddA[j];
          qvB+=rtu*duB[j]+rtd*ddB[j];  svB+=duB[j]-ddB[j];
        }
      }
      sQp[lane*9+wave]=qvA;      sSp[lane*9+wave]=svA;
      sQp[(lane+64)*9+wave]=qvB; sSp[(lane+64)*9+wave]=svB;
    } else {
      // wave1: weight reductions S1s/S2s/sgl (bit-identical), LS/SP precompute,
      // gamma publish, then pass B.
      float g1l=0.f,g2l=0.f,sgl=0.f;
#pragma unroll
      for (int h=0;h<2;++h){
        const int nn=lane+h*64;
        const float Qn=sQnP[nn]+sQnP[nn+128]+sQnP[nn+256]+sQnP[nn+384];
        const float m1=QmaxS-gammaS*sDM[nn], m2=QminS-gammaS*sDm[nn];
        const float inner=fmaxf(m1,m2), ph=fmaxf(Qn,inner);
        const float gQn=(Qn==ph?1.f:0.f)/((inner==ph)?2.f:1.f);
        const float gIn=(inner==ph?1.f:0.f)/((Qn==ph)?2.f:1.f);
        const float gm1=gIn*(m1==inner?1.f:0.f)/((m2==inner)?2.f:1.f);
        const float gm2=gIn*(m2==inner?1.f:0.f)/((m1==inner)?2.f:1.f);
        const float gq=gQn*INVN;
        g1l+=gm1; g2l+=gm2; sgl+=gm1*sDM[nn]+gm2*sDm[nn];
        const float r2=sS2[nn]+sLS[nn]-sSP[nn]-sOm[nn];
        const float r220=TWO_RHO*r2;
        const float lsnew=fmaxf(sLS[nn]-LR*(gq*VOLL+r220),0.f);
        const float spnew=fmaxf(sSP[nn]-LR*(gq*VOSP-r220),0.f);
        if (h==0){ lsR0=lsnew; spR0=spnew; } else { lsR1=lsnew; spR1=spnew; }
      }
#pragma unroll
      for (int off=32; off; off>>=1){
        g1l+=__shfl_xor(g1l,off,64); g2l+=__shfl_xor(g2l,off,64); sgl+=__shfl_xor(sgl,off,64);
      }
      const float S1s=g1l, S2s=g2l;   // uniform across wave after butterfly
      if (t_own==0 && lane==0)
        gstore64(gamW, pack(fmaxf(gammaS-LR*(epsv-INVN*sgl),0.f), tg2));
      // pass B (deps: consume + barrier A only — NOT pass A)
      const float r3=__shfl(r3reg,0,64), r4=__shfl(r4reg,0,64), rP=__shfl(rPreg,0,64);
      float pQx=0.f,pQn2=0.f,pr3=0.f,pr4=0.f,pP=0.f;
#pragma unroll
      for (int i=0;i<2;++i){
        if (i==0 || hasG1){
          const int g = lane + i*64;
          const float rupS=sAccU[g], rdnS=sAccD[g];
          const float Pold=sP[g], ru=sRuC[g], rd=sRdC[g];
          const float duMo=duMr[i], ddMo=ddMr[i], dumo=dumr[i], ddmo=ddmr[i];
          const float r5 =fmaxf(Pold+ru-sPmax[g],0.f);
          const float r6 =fmaxf(sPmin[g]-Pold+rd,0.f);
          const float r9 =fmaxf(duMo-ru,0.f), r10=fmaxf(ddMo-rd,0.f);
          const float r11=fmaxf(dumo-ru,0.f), r12=fmaxf(ddmo-rd,0.f);
          const float rampg=sPmax[g];
          float gP=sB[g]+TWO_RHO*(rP+r5-r6);
          if (t_own>0){
            const float dp=Pold-unpackv(i==0?xm0:xm1);
            gP+=TWO_RHO*fmaxf(fabsf(dp)-rampg,0.f)*(dp>=0.f?1.f:-1.f);
          }
          if (t_own<T_-1){
            const float dq=unpackv(i==0?xp0:xp1)-Pold;
            gP-=TWO_RHO*fmaxf(fabsf(dq)-rampg,0.f)*(dq>=0.f?1.f:-1.f);
          }
          const float Pn=fminf(fmaxf(Pold-LR*gP,sPmin[g]),sPmax[g]);
          sP[g]=Pn; gstore64(&ppW[g], pack(Pn,tg2));
          const float rtuB=2.f*sB[g], rtdB=0.5f*sB[g];
          sRuN[g]=fmaxf(ru-LR*(0.05f*sB[g]+TWO_RHO*(r5-rupS-r9-r11)),0.f);
          sRdN[g]=fmaxf(rd-LR*(0.02f*sB[g]+TWO_RHO*(r6-rdnS-r10-r12)),0.f);
          const float duMn=fmaxf(duMo-LR*(INVN*S1s*rtuB+TWO_RHO*( r3+r9 )),0.f);
          const float ddMn=fmaxf(ddMo-LR*(INVN*S1s*rtdB+TWO_RHO*(-r3+r10)),0.f);
          const float dumn=fmaxf(dumo-LR*(INVN*S2s*rtuB+TWO_RHO*( r4+r11)),0.f);
          const float ddmn=fmaxf(ddmo-LR*(INVN*S2s*rtdB+TWO_RHO*(-r4+r12)),0.f);
          duMr[i]=duMn; ddMr[i]=ddMn; dumr[i]=dumn; ddmr[i]=ddmn;
          pQx+=rtuB*duMn+rtdB*ddMn; pQn2+=rtuB*dumn+rtdB*ddmn;
          pr3+=duMn-ddMn; pr4+=dumn-ddmn; pP+=Pn;
        }
      }
#pragma unroll
      for (int off=32; off; off>>=1){
        pQx+=__shfl_down(pQx,off,64);  pQn2+=__shfl_down(pQn2,off,64);
        pr3+=__shfl_down(pr3,off,64);  pr4+=__shfl_down(pr4,off,64);
        pP +=__shfl_down(pP,off,64);
      }
      if (lane==0){
        const float LSMn=fmaxf(lsm-LR*(INVN*S1s*VOLL+TWO_RHO*r3),0.f);
        const float SPMn=fmaxf(spm-LR*(INVN*S1s*VOSP-TWO_RHO*r3),0.f);
        const float LSmn=fmaxf(lsn-LR*(INVN*S2s*VOLL+TWO_RHO*r4),0.f);
        const float SPmn=fmaxf(spn-LR*(INVN*S2s*VOSP-TWO_RHO*r4),0.f);
        lsm=LSMn; spm=SPMn; lsn=LSmn; spn=SPmn;
        gstore64(&qsW[0], pack(pQx + VOLL*LSMn + VOSP*SPMn, tg2));   // qs lands EARLY
        gstore64(&qsW[1], pack(pQn2 + VOLL*LSmn + VOSP*SPmn, tg2));
        r3reg=pr3 + LSMn - SPMn - omaxT;
        r4reg=pr4 + LSmn - SPmn - ominT;
        rPreg=pP - fctT;
      }
    }
    __syncthreads();   // barrier C (last barrier of the iteration)

    // ---- PHASE 3: pass-A waves — nothing (shadow moved to next phase 1);
    //               wave1 {combine + qnp publish + qs/gamma spin -> sScal[parN]} ----
    if (!pA){
      // pre-issue next-state qs/gamma polls (latency hides under combine)
      u64 yq0=0, yq1=0, yg;
      if (lane<T_){ yq0=gload64(&qsN[lane*16]); yq1=gload64(&qsN[lane*16+1]); }
      yg=gload64(gamN);
      // combine: publish qnp ASAP. Reads only sQp/sSp (written phase 2, protected
      // by barrier C now and by barrier A of k+1 against next-iter writers) and
      // the register-precomputed LS/SP updates.
#pragma unroll
      for (int h=0;h<2;++h){
        const int nn=lane+h*64;
        const float LSn=(h==0?lsR0:lsR1), SPn=(h==0?spR0:spR1);
        sLS[nn]=LSn; sSP[nn]=SPn;
        float q=0.f,s=0.f;
#pragma unroll
        for (int w=0;w<8;++w){ q+=sQp[nn*9+w]; s+=sSp[nn*9+w]; }
        sS2[nn]=s;
        q += VOLL*LSn + VOSP*SPn;
        gstore64(&qnpW[nn], pack(q,tg2));
      }
      // spin for next-state qs/gamma; reduce Qmax/Qmin (same butterfly order ->
      // bit-identical) into slot parN.
      for (;;){
        bool pend=false;
        if (lane<T_){
          if (unpackt(yq0)!=tg2){ yq0=gload64(&qsN[lane*16]);   pend=true; }
          if (unpackt(yq1)!=tg2){ yq1=gload64(&qsN[lane*16+1]); pend=true; }
        }
        if (unpackt(yg)!=tg2){ yg=gload64(gamN); pend=true; }
        if (!pend) break;
        __builtin_amdgcn_s_sleep(1);
      }
      float qmx=(lane<T_)?unpackv(yq0):0.f, qmn=(lane<T_)?unpackv(yq1):0.f;
#pragma unroll
      for (int off=32; off; off>>=1){ qmx+=__shfl_xor(qmx,off,64); qmn+=__shfl_xor(qmn,off,64); }
      if (lane==0){ sScal[parN*3]=qmx; sScal[parN*3+1]=qmn; sScal[parN*3+2]=unpackv(yg); }
    }
    // no barrier here: barrier A of the next iteration orders phase-3 writes
    // (sLS/sSP/sS2/sScal) and the phase-1 shadow writes (sAcc) against readers.
  }
}

extern "C" void kernel_launch(void* const* d_in, const int* in_sizes, int n_in,
                              void* d_out, int out_size, void* d_ws, size_t ws_size,
                              hipStream_t stream) {
  const float* forecast = (const float*)d_in[0];
  const float* omega    = (const float*)d_in[1];
  const float* omin     = (const float*)d_in[2];
  const float* omax     = (const float*)d_in[3];
  const float* eps      = (const float*)d_in[4];
  const float* pmin     = (const float*)d_in[5];
  const float* pmax     = (const float*)d_in[6];
  const float* bG       = (const float*)d_in[7];
  const float* cG       = (const float*)d_in[8];
  float* out = (float*)d_out;
  float* ws  = (float*)d_ws;
  void* args[] = { &forecast, &omega, &omin, &omax, &eps, &pmin, &pmax, &bG, &cG, &out, &ws };
  hipLaunchCooperativeKernel((const void*)dro_kernel, dim3(NBLK), dim3(NTHR),
                             args, 0, stream);
}

// Round 9
// 406.216 us; speedup vs baseline: 1.5198x; 1.0527x over previous
//
#include <hip/hip_runtime.h>
#include <hip/hip_cooperative_groups.h>

namespace cg = cooperative_groups;

#define G_ 100
#define T_ 24
#define NSC 128
#define BATCH 8
#define NITER 40
#define NBLK (BATCH*T_)     // 192 WGs: one (batch,t) per WG
#define NTHR 512            // 8 waves -> 2 waves/SIMD
#define GMAX 15             // pass-A g's per wave (7 waves cover 100 g)

typedef unsigned long long u64;

// (tag<<32 | float) pairs via relaxed agent-scope 8B atomics (LLC-coherent).
// Consumers spin on tags; producers never fence. Depth-3 buffers, monotonic tags.
__device__ __forceinline__ u64 gload64(const u64* p){
  return __hip_atomic_load(p, __ATOMIC_RELAXED, __HIP_MEMORY_SCOPE_AGENT);
}
__device__ __forceinline__ void gstore64(u64* p, u64 v){
  __hip_atomic_store(p, v, __ATOMIC_RELAXED, __HIP_MEMORY_SCOPE_AGENT);
}
__device__ __forceinline__ u64 pack(float v, unsigned tag){
  return ((u64)tag<<32) | (u64)__float_as_uint(v);
}
__device__ __forceinline__ float unpackv(u64 x){ return __uint_as_float((unsigned)x); }
__device__ __forceinline__ unsigned unpackt(u64 x){ return (unsigned)(x>>32); }

// full-block reduce (init/epilogue only)
__device__ __forceinline__ void blockReduce2(float& a, float& b, float* sR){
#pragma unroll
  for (int off=32; off; off>>=1){ a+=__shfl_down(a,off,64); b+=__shfl_down(b,off,64); }
  const int w = threadIdx.x>>6;
  __syncthreads();
  if ((threadIdx.x&63)==0){ sR[w]=a; sR[8+w]=b; }
  __syncthreads();
  a=0.f; b=0.f;
#pragma unroll
  for (int i=0;i<8;++i){ a+=sR[i]; b+=sR[8+i]; }
}

__global__ __launch_bounds__(NTHR, 1) void dro_kernel(
    const float* __restrict__ forecast, const float* __restrict__ omega,
    const float* __restrict__ om_min, const float* __restrict__ om_max,
    const float* __restrict__ eps_in, const float* __restrict__ pmin_g,
    const float* __restrict__ pmax_g, const float* __restrict__ bG,
    const float* __restrict__ cG, float* __restrict__ out, float* __restrict__ ws)
{
  constexpr float LR=2e-4f, VOLL=1000.f, VOSP=50.f, TWO_RHO=20.f, INVN=1.f/128.f;
  const int blk=blockIdx.x;
  const int b=blk&7;            // round-robin XCD: batch stays XCD-affine
  const int t_own=blk>>3;
  const int tid=threadIdx.x, wave=tid>>6, lane=tid&63;
  // pass-A g ownership: wave1 is EXEMPT (dedicated pass-B/combine wave).
  // waves {0,2,3,4,5,6,7} own {14,15,15,14,14,14,14} g's = 100.
  int gbase, gcnt;
  if      (wave==0){ gbase=0;  gcnt=14; }
  else if (wave==1){ gbase=0;  gcnt=0;  }
  else if (wave==2){ gbase=14; gcnt=15; }
  else if (wave==3){ gbase=29; gcnt=15; }
  else             { gbase=44+(wave-4)*14; gcnt=14; }
  const bool pA = (wave!=1);

  __shared__ float sRu[2][G_], sRd[2][G_];   // double-buffered: passA reads cur, passB writes nxt
  __shared__ float sP[G_];                   // wave1-only during loop; epilogue reads
  __shared__ float sAccU[G_], sAccD[G_];
  __shared__ float sB[G_], sPmin[G_], sPmax[G_], sC[G_];
  __shared__ float sLS[NSC], sSP[NSC], sOm[NSC];
  __shared__ float sQn[NSC], sDM[NSC], sDm[NSC], sS2[NSC];
  __shared__ float sQp[NSC*9], sSp[NSC*9];   // [n][wave] stride 9; column 1 fixed 0
  __shared__ float sQnP[NTHR];
  __shared__ float sRed[40];
  __shared__ float sScal[8];   // parity slots: [par*3+{0,1,2}] = Qmax,Qmin,gamma for state k (par=k&1)

  u64* W = (u64*)ws;
  u64* QNP = W;                       // [3][8][24][128]
  u64* PP  = W + 73728;               // [3][8][24][128] (first 100 used)
  u64* QS  = W + 147456;              // [3][8][24][16]  (Qmax@0, Qmin@1)
  u64* GAM = W + 156672;              // [3][8][16]
  u64* ST1 = W + 157056;              // [8][24][16]

  const float epsv  = eps_in[b];
  const float omaxT = om_max[b*T_ + t_own];
  const float ominT = om_min[b*T_ + t_own];
  const float fctT  = forecast[b*T_ + t_own];

  // register-resident d_up/d_dn: lane holds n=lane (A) and n=lane+64 (B)
  float duA[GMAX], duB[GMAX], ddA[GMAX], ddB[GMAX];
  // wave1-resident pass-B state (2 g/lane: g=lane, g=lane+64 for lane<36)
  float duMr[2]={0.f,0.f}, ddMr[2]={0.f,0.f}, dumr[2]={0.f,0.f}, ddmr[2]={0.f,0.f};
  float lsm=0.f, spm=0.f, lsn=0.f, spn=0.f;     // wave1-lane0: LSM,SPM,LSm,SPm
  float r3reg=0.f, r4reg=0.f, rPreg=0.f;        // wave1-lane0

  // ---------------- init ----------------
  if (tid<G_){
    sB[tid]=bG[tid]; sPmin[tid]=pmin_g[tid]; sPmax[tid]=pmax_g[tid]; sC[tid]=cG[tid];
    sRu[0][tid]=0.f; sRd[0][tid]=0.f;
    sAccU[tid]=0.f; sAccD[tid]=0.f;
  }
  if (tid<NSC){
    const int nn=tid;
    sLS[nn]=0.f; sSP[nn]=0.f; sS2[nn]=0.f;
    sOm[nn]=omega[(b*NSC+nn)*T_+t_own];
    float dM=0.f,dm=0.f;
    for (int t=0;t<T_;++t){
      float o=omega[(b*NSC+nn)*T_+t];
      dM+=om_max[b*T_+t]-o; dm+=o-om_min[b*T_+t];
    }
    sDM[nn]=dM; sDm[nn]=dm;
    sQp[nn*9+1]=0.f; sSp[nn*9+1]=0.f;   // wave1 pass-A column: permanently zero
  }
  if (tid<6) sScal[tid]=0.f;            // state-0 Qmax/Qmin/gamma = 0 (both parity slots)
  __syncthreads();
#pragma unroll
  for (int j=0;j<GMAX;++j){ duA[j]=0.f; duB[j]=0.f; ddA[j]=0.f; ddB[j]=0.f; }
  {
    float p0=0.f;
    if (tid<G_){
      p0=0.5f*(sPmin[tid]+sPmax[tid]);
      sP[tid]=p0;
      gstore64(&PP[b*3072 + t_own*128 + tid], pack(p0,1u));
    }
    if (tid<NSC) gstore64(&QNP[b*3072 + t_own*128 + tid], pack(0.f,1u));
    float rp=p0, dum0=0.f;
    blockReduce2(rp,dum0,sRed);
    r3reg=-omaxT; r4reg=-ominT; rPreg=rp-fctT;   // wave1-lane0's copies are live
  }
  __syncthreads();

  for (int k=0;k<=NITER;++k){
    const unsigned tg  = (unsigned)(k+1);
    const unsigned tg2 = (unsigned)(k+2);
    const int rb = k%3, wb = (k+1)%3;
    const int kb = k&1, nbuf = kb^1;
    const int par = k&1, parN = par^1;
    float* sRuC = sRu[kb];  float* sRdC = sRd[kb];
    float* sRuN = sRu[nbuf]; float* sRdN = sRd[nbuf];
    const u64* qnpR = QNP + rb*24576 + b*3072;
    const u64* ppR  = PP  + rb*24576 + b*3072;
    u64* qnpW = QNP + wb*24576 + b*3072 + t_own*128;
    u64* ppW  = PP  + wb*24576 + b*3072 + t_own*128;
    u64* qsW  = QS  + (wb*BATCH + b)*T_*16 + t_own*16;
    const u64* qsN = QS + (wb*BATCH + b)*T_*16;   // consumed at PHASE 3 this iter (tag tg2)
    u64* gamW = GAM + (wb*BATCH + b)*16;
    const u64* gamN = gamW;

    // ---- PHASE 1: consume qnp (all) + neighbor P (wave1): pre-issue, unified spin ----
    const int n = tid&127, sb0 = (tid>>7)*6;
    const bool w1 = (wave==1), hasG1 = w1 && (lane<36);
    const bool doP = w1 && (k<NITER);
    u64 xq[6];
#pragma unroll
    for (int s=0;s<6;++s) xq[s]=gload64(&qnpR[(sb0+s)*128+n]);
    u64 xm0=0,xm1=0,xp0=0,xp1=0;
    if (doP){
      if (t_own>0){
        xm0=gload64(&ppR[(t_own-1)*128+lane]);
        if (hasG1) xm1=gload64(&ppR[(t_own-1)*128+lane+64]);
      }
      if (t_own<T_-1){
        xp0=gload64(&ppR[(t_own+1)*128+lane]);
        if (hasG1) xp1=gload64(&ppR[(t_own+1)*128+lane+64]);
      }
    }
    for (;;){
      bool pend=false;
#pragma unroll
      for (int s=0;s<6;++s)
        if (unpackt(xq[s])!=tg){ xq[s]=gload64(&qnpR[(sb0+s)*128+n]); pend=true; }
      if (doP){
        if (t_own>0){
          if (unpackt(xm0)!=tg){ xm0=gload64(&ppR[(t_own-1)*128+lane]); pend=true; }
          if (hasG1 && unpackt(xm1)!=tg){ xm1=gload64(&ppR[(t_own-1)*128+lane+64]); pend=true; }
        }
        if (t_own<T_-1){
          if (unpackt(xp0)!=tg){ xp0=gload64(&ppR[(t_own+1)*128+lane]); pend=true; }
          if (hasG1 && unpackt(xp1)!=tg){ xp1=gload64(&ppR[(t_own+1)*128+lane+64]); pend=true; }
        }
      }
      if (!pend) break;
      __builtin_amdgcn_s_sleep(1);
    }
    sQnP[tid]=unpackv(xq[0])+unpackv(xq[1])+unpackv(xq[2])
             +unpackv(xq[3])+unpackv(xq[4])+unpackv(xq[5]);
    __syncthreads();   // barrier A

    if (k==NITER){  // ---------------- final: phi + outputs ----------------
      // state-40 Qmax/Qmin/gamma were consumed+reduced at phase 3 of k=39 into slot par
      const float Qm=sScal[par*3], Qn2=sScal[par*3+1], gam=sScal[par*3+2];
      if (tid<NSC){
        const float qsum=sQnP[tid]+sQnP[tid+128]+sQnP[tid+256]+sQnP[tid+384];
        const float ph=fmaxf(qsum,fmaxf(Qm-gam*sDM[tid],Qn2-gam*sDm[tid]));
        sQn[tid]=ph;
        if (t_own==0) out[76800 + b*NSC + tid]=ph;
      }
      float st=0.f, dum0=0.f;
      if (tid<G_){
        const int g=tid;
        const float Pv=sP[g];
        const float costv=sB[g]*Pv+sC[g];
        st=costv + 0.05f*sB[g]*sRuC[g] + 0.02f*sB[g]*sRdC[g];
        const int o=b*2400 + g*T_ + t_own;
        out[o]=Pv;
        out[19200+o]=sRuC[g];
        out[38400+o]=sRdC[g];
        out[57600+o]=costv;
      }
      blockReduce2(st,dum0,sRed);
      if (tid==0) gstore64(&ST1[(b*T_+t_own)*16], pack(st,99u));
      if (t_own==0){
        if (tid==0) out[77824+b]=gam;
        float s1=0.f;
        if (tid<64){
          u64 xs = (lane<T_)? gload64(&ST1[(b*T_+lane)*16]) : pack(0.f,99u);
          while (unpackt(xs)!=99u){ __builtin_amdgcn_s_sleep(1); xs=gload64(&ST1[(b*T_+lane)*16]); }
          s1=unpackv(xs);
        }
        float pm=(tid<NSC)? sQn[tid] : 0.f;
        blockReduce2(pm,s1,sRed);
        if (tid==0) out[77832+b] = s1 + pm*INVN + epsv*gam;
      }
      break;
    }

    // ---- PHASE 2: pass A (7 waves, with per-lane weight recompute)
    //               CONCURRENT WITH wave1 {weights-reduce + gamma + pass B + qs publish} ----
    const float QmaxS=sScal[par*3], QminS=sScal[par*3+1], gammaS=sScal[par*3+2];
    float lsR0=0.f, lsR1=0.f, spR0=0.f, spR1=0.f;   // wave1: precomputed LS/SP updates
    if (pA){
      // redundant per-lane weights for n=lane (A) and n=lane+64 (B): bit-identical.
      float gqA=0.f,r220A=0.f,gqB=0.f,r220B=0.f;
#pragma unroll
      for (int h=0;h<2;++h){
        const int nn=lane+h*64;
        const float Qn=sQnP[nn]+sQnP[nn+128]+sQnP[nn+256]+sQnP[nn+384];
        const float m1=QmaxS-gammaS*sDM[nn], m2=QminS-gammaS*sDm[nn];
        const float inner=fmaxf(m1,m2), ph=fmaxf(Qn,inner);
        const float gQn=(Qn==ph?1.f:0.f)/((inner==ph)?2.f:1.f);
        const float gq=gQn*INVN;
        const float r2=sS2[nn]+sLS[nn]-sSP[nn]-sOm[nn];
        const float r220=TWO_RHO*r2;
        if (h==0){ gqA=gq; r220A=r220; } else { gqB=gq; r220B=r220; }
      }
      float qvA=0.f,qvB=0.f,svA=0.f,svB=0.f;
#pragma unroll
      for (int j=0;j<GMAX;++j){
        if (j<gcnt){
          const int g=gbase+j;
          const float bg=sB[g];
          const float rtu=2.f*bg, rtd=0.5f*bg;
          const float ru=sRuC[g], rd=sRdC[g];
          const float r7A=fmaxf(duA[j]-ru,0.f), r8A=fmaxf(ddA[j]-rd,0.f);
          const float r7B=fmaxf(duB[j]-ru,0.f), r8B=fmaxf(ddB[j]-rd,0.f);
          duA[j]=fmaxf(duA[j]-LR*(gqA*rtu+(r220A+TWO_RHO*r7A)),0.f);
          ddA[j]=fmaxf(ddA[j]-LR*(gqA*rtd+(TWO_RHO*r8A-r220A)),0.f);
          duB[j]=fmaxf(duB[j]-LR*(gqB*rtu+(r220B+TWO_RHO*r7B)),0.f);
          ddB[j]=fmaxf(ddB[j]-LR*(gqB*rtd+(TWO_RHO*r8B-r220B)),0.f);
          qvA+=rtu*duA[j]+rtd*ddA[j];  svA+=duA[j]-ddA[j];
          qvB+=rtu*duB[j]+rtd*ddB[j];  svB+=duB[j]-ddB[j];
        }
      }
      sQp[lane*9+wave]=qvA;      sSp[lane*9+wave]=svA;
      sQp[(lane+64)*9+wave]=qvB; sSp[(lane+64)*9+wave]=svB;
    } else {
      // wave1: weight reductions S1s/S2s/sgl (bit-identical), LS/SP precompute,
      // gamma publish, then pass B.
      float g1l=0.f,g2l=0.f,sgl=0.f;
#pragma unroll
      for (int h=0;h<2;++h){
        const int nn=lane+h*64;
        const float Qn=sQnP[nn]+sQnP[nn+128]+sQnP[nn+256]+sQnP[nn+384];
        const float m1=QmaxS-gammaS*sDM[nn], m2=QminS-gammaS*sDm[nn];
        const float inner=fmaxf(m1,m2), ph=fmaxf(Qn,inner);
        const float gQn=(Qn==ph?1.f:0.f)/((inner==ph)?2.f:1.f);
        const float gIn=(inner==ph?1.f:0.f)/((Qn==ph)?2.f:1.f);
        const float gm1=gIn*(m1==inner?1.f:0.f)/((m2==inner)?2.f:1.f);
        const float gm2=gIn*(m2==inner?1.f:0.f)/((m1==inner)?2.f:1.f);
        const float gq=gQn*INVN;
        g1l+=gm1; g2l+=gm2; sgl+=gm1*sDM[nn]+gm2*sDm[nn];
        const float r2=sS2[nn]+sLS[nn]-sSP[nn]-sOm[nn];
        const float r220=TWO_RHO*r2;
        const float lsnew=fmaxf(sLS[nn]-LR*(gq*VOLL+r220),0.f);
        const float spnew=fmaxf(sSP[nn]-LR*(gq*VOSP-r220),0.f);
        if (h==0){ lsR0=lsnew; spR0=spnew; } else { lsR1=lsnew; spR1=spnew; }
      }
#pragma unroll
      for (int off=32; off; off>>=1){
        g1l+=__shfl_xor(g1l,off,64); g2l+=__shfl_xor(g2l,off,64); sgl+=__shfl_xor(sgl,off,64);
      }
      const float S1s=g1l, S2s=g2l;   // uniform across wave after butterfly
      if (t_own==0 && lane==0)
        gstore64(gamW, pack(fmaxf(gammaS-LR*(epsv-INVN*sgl),0.f), tg2));
      // pass B (deps: consume + barrier A only — NOT pass A)
      const float r3=__shfl(r3reg,0,64), r4=__shfl(r4reg,0,64), rP=__shfl(rPreg,0,64);
      float pQx=0.f,pQn2=0.f,pr3=0.f,pr4=0.f,pP=0.f;
#pragma unroll
      for (int i=0;i<2;++i){
        if (i==0 || hasG1){
          const int g = lane + i*64;
          const float rupS=sAccU[g], rdnS=sAccD[g];
          const float Pold=sP[g], ru=sRuC[g], rd=sRdC[g];
          const float duMo=duMr[i], ddMo=ddMr[i], dumo=dumr[i], ddmo=ddmr[i];
          const float r5 =fmaxf(Pold+ru-sPmax[g],0.f);
          const float r6 =fmaxf(sPmin[g]-Pold+rd,0.f);
          const float r9 =fmaxf(duMo-ru,0.f), r10=fmaxf(ddMo-rd,0.f);
          const float r11=fmaxf(dumo-ru,0.f), r12=fmaxf(ddmo-rd,0.f);
          const float rampg=sPmax[g];
          float gP=sB[g]+TWO_RHO*(rP+r5-r6);
          if (t_own>0){
            const float dp=Pold-unpackv(i==0?xm0:xm1);
            gP+=TWO_RHO*fmaxf(fabsf(dp)-rampg,0.f)*(dp>=0.f?1.f:-1.f);
          }
          if (t_own<T_-1){
            const float dq=unpackv(i==0?xp0:xp1)-Pold;
            gP-=TWO_RHO*fmaxf(fabsf(dq)-rampg,0.f)*(dq>=0.f?1.f:-1.f);
          }
          const float Pn=fminf(fmaxf(Pold-LR*gP,sPmin[g]),sPmax[g]);
          sP[g]=Pn; gstore64(&ppW[g], pack(Pn,tg2));
          const float rtuB=2.f*sB[g], rtdB=0.5f*sB[g];
          sRuN[g]=fmaxf(ru-LR*(0.05f*sB[g]+TWO_RHO*(r5-rupS-r9-r11)),0.f);
          sRdN[g]=fmaxf(rd-LR*(0.02f*sB[g]+TWO_RHO*(r6-rdnS-r10-r12)),0.f);
          const float duMn=fmaxf(duMo-LR*(INVN*S1s*rtuB+TWO_RHO*( r3+r9 )),0.f);
          const float ddMn=fmaxf(ddMo-LR*(INVN*S1s*rtdB+TWO_RHO*(-r3+r10)),0.f);
          const float dumn=fmaxf(dumo-LR*(INVN*S2s*rtuB+TWO_RHO*( r4+r11)),0.f);
          const float ddmn=fmaxf(ddmo-LR*(INVN*S2s*rtdB+TWO_RHO*(-r4+r12)),0.f);
          duMr[i]=duMn; ddMr[i]=ddMn; dumr[i]=dumn; ddmr[i]=ddmn;
          pQx+=rtuB*duMn+rtdB*ddMn; pQn2+=rtuB*dumn+rtdB*ddmn;
          pr3+=duMn-ddMn; pr4+=dumn-ddmn; pP+=Pn;
        }
      }
#pragma unroll
      for (int off=32; off; off>>=1){
        pQx+=__shfl_down(pQx,off,64);  pQn2+=__shfl_down(pQn2,off,64);
        pr3+=__shfl_down(pr3,off,64);  pr4+=__shfl_down(pr4,off,64);
        pP +=__shfl_down(pP,off,64);
      }
      if (lane==0){
        const float LSMn=fmaxf(lsm-LR*(INVN*S1s*VOLL+TWO_RHO*r3),0.f);
        const float SPMn=fmaxf(spm-LR*(INVN*S1s*VOSP-TWO_RHO*r3),0.f);
        const float LSmn=fmaxf(lsn-LR*(INVN*S2s*VOLL+TWO_RHO*r4),0.f);
        const float SPmn=fmaxf(spn-LR*(INVN*S2s*VOSP-TWO_RHO*r4),0.f);
        lsm=LSMn; spm=SPMn; lsn=LSmn; spn=SPmn;
        gstore64(&qsW[0], pack(pQx + VOLL*LSMn + VOSP*SPMn, tg2));   // qs lands EARLY
        gstore64(&qsW[1], pack(pQn2 + VOLL*LSmn + VOSP*SPmn, tg2));
        r3reg=pr3 + LSMn - SPMn - omaxT;
        r4reg=pr4 + LSmn - SPmn - ominT;
        rPreg=pP - fctT;
      }
    }
    __syncthreads();   // barrier C (last barrier of the iteration)

    // ---- PHASE 3: shadow (pass-A waves) CONCURRENT WITH wave1
    //               {combine + qnp publish, then consume qs/gamma for next iter} ----
    if (pA){
#pragma unroll
      for (int j=0;j<GMAX;++j){
        if (j<gcnt){
          const int g=gbase+j;
          const float ru=sRuN[g], rd=sRdN[g];   // NEW Ru/Rd (pass B done at barrier C)
          float aU=fmaxf(duA[j]-ru,0.f)+fmaxf(duB[j]-ru,0.f);
          float aD=fmaxf(ddA[j]-rd,0.f)+fmaxf(ddB[j]-rd,0.f);
#pragma unroll
          for (int off=32; off; off>>=1){ aU+=__shfl_xor(aU,off,64); aD+=__shfl_xor(aD,off,64); }
          if (lane==0){ sAccU[g]=aU; sAccD[g]=aD; }
        }
      }
    } else {
      // pre-issue next-state qs/gamma polls (latency hides under combine)
      u64 yq0=0, yq1=0, yg;
      if (lane<T_){ yq0=gload64(&qsN[lane*16]); yq1=gload64(&qsN[lane*16+1]); }
      yg=gload64(gamN);
      // combine: publish qnp ASAP. Reads only sQp/sSp (written phase 2, protected
      // by barrier C now and by barrier A of k+1 against next-iter writers) and
      // the register-precomputed LS/SP updates -> no sQnP read here (race-free).
#pragma unroll
      for (int h=0;h<2;++h){
        const int nn=lane+h*64;
        const float LSn=(h==0?lsR0:lsR1), SPn=(h==0?spR0:spR1);
        sLS[nn]=LSn; sSP[nn]=SPn;
        float q=0.f,s=0.f;
#pragma unroll
        for (int w=0;w<8;++w){ q+=sQp[nn*9+w]; s+=sSp[nn*9+w]; }
        sS2[nn]=s;
        q += VOLL*LSn + VOSP*SPn;
        gstore64(&qnpW[nn], pack(q,tg2));
      }
      // spin for next-state qs/gamma; reduce Qmax/Qmin (same butterfly order as
      // the old wave0 top-of-iteration path -> bit-identical) into slot parN.
      for (;;){
        bool pend=false;
        if (lane<T_){
          if (unpackt(yq0)!=tg2){ yq0=gload64(&qsN[lane*16]);   pend=true; }
          if (unpackt(yq1)!=tg2){ yq1=gload64(&qsN[lane*16+1]); pend=true; }
        }
        if (unpackt(yg)!=tg2){ yg=gload64(gamN); pend=true; }
        if (!pend) break;
        __builtin_amdgcn_s_sleep(1);
      }
      float qmx=(lane<T_)?unpackv(yq0):0.f, qmn=(lane<T_)?unpackv(yq1):0.f;
#pragma unroll
      for (int off=32; off; off>>=1){ qmx+=__shfl_xor(qmx,off,64); qmn+=__shfl_xor(qmn,off,64); }
      if (lane==0){ sScal[parN*3]=qmx; sScal[parN*3+1]=qmn; sScal[parN*3+2]=unpackv(yg); }
    }
    // no barrier here: barrier A of the next iteration orders phase-3 writes
    // (sLS/sSP/sS2/sAcc/sScal) against all next-iteration readers.
  }
}

extern "C" void kernel_launch(void* const* d_in, const int* in_sizes, int n_in,
                              void* d_out, int out_size, void* d_ws, size_t ws_size,
                              hipStream_t stream) {
  const float* forecast = (const float*)d_in[0];
  const float* omega    = (const float*)d_in[1];
  const float* omin     = (const float*)d_in[2];
  const float* omax     = (const float*)d_in[3];
  const float* eps      = (const float*)d_in[4];
  const float* pmin     = (const float*)d_in[5];
  const float* pmax     = (const float*)d_in[6];
  const float* bG       = (const float*)d_in[7];
  const float* cG       = (const float*)d_in[8];
  float* out = (float*)d_out;
  float* ws  = (float*)d_ws;
  void* args[] = { &forecast, &omega, &omin, &omax, &eps, &pmin, &pmax, &bG, &cG, &out, &ws };
  hipLaunchCooperativeKernel((const void*)dro_kernel, dim3(NBLK), dim3(NTHR),
                             args, 0, stream);
}